// Round 1
// baseline (5695.796 us; speedup 1.0000x reference)
//
#include <hip/hip_runtime.h>

#define N_NODES 50000
#define N_EDGES 800000
#define NSTEPS 3

// ---------- helpers ----------

// load float from either bf16-packed or fp32 array, chosen by runtime flag
__device__ __forceinline__ float ldf(const void* p, long i, int bf) {
    if (bf) {
        unsigned int u = ((const unsigned short*)p)[i];
        u <<= 16;
        return __uint_as_float(u);
    }
    return ((const float*)p)[i];
}

__device__ __forceinline__ unsigned short f2bf(float f) {
    unsigned int u = __float_as_uint(f);
    u = u + 0x7FFFu + ((u >> 16) & 1u);   // round-to-nearest-even
    return (unsigned short)(u >> 16);
}

// jax.nn.gelu default (approximate=True, tanh form)
__device__ __forceinline__ float gelu_f(float x) {
    // tanh(z) = 1 - 2/(exp(2z)+1), z = 0.7978845608*(x + 0.044715 x^3)
    float y = 1.5957691216057308f * (x + 0.044715f * x * x * x);
    float e = __expf(y);
    float t = 1.0f - 2.0f / (e + 1.0f);
    return 0.5f * x * (1.0f + t);
}

// acc[i] += sum_{k=0..63} xs[r0+i][k] * W[wbase + k*64 + col]
__device__ __forceinline__ void acc_part(float acc[16], const float (*xs)[64], int r0,
                                         const void* W, long wbase, int col, int bf) {
    for (int k = 0; k < 64; k += 4) {
        float wa = ldf(W, wbase + (long)(k + 0) * 64 + col, bf);
        float wb = ldf(W, wbase + (long)(k + 1) * 64 + col, bf);
        float wc = ldf(W, wbase + (long)(k + 2) * 64 + col, bf);
        float wd = ldf(W, wbase + (long)(k + 3) * 64 + col, bf);
#pragma unroll
        for (int i = 0; i < 16; i++) {
            const float4 x = *(const float4*)&xs[r0 + i][k];
            acc[i] = fmaf(x.x, wa, fmaf(x.y, wb, fmaf(x.z, wc, fmaf(x.w, wd, acc[i]))));
        }
    }
}

// ---------- dtype detect ----------
// ln_n_scale is all ones: first 32-bit word is 0x3F803F80 if bf16-packed, 0x3F800000 if fp32.
__global__ void detect_kernel(const void* probe, int* flag) {
    if (threadIdx.x == 0 && blockIdx.x == 0) {
        unsigned int w = *(const unsigned int*)probe;
        *flag = (w == 0x3F803F80u) ? 1 : 0;
    }
}

// ---------- embedder: [R, DIN] -> MLP(DIN,64,64,64) -> fp32 [R,64] ----------
template <int DIN>
__global__ __launch_bounds__(256) void embed_kernel(
    const void* __restrict__ xin, const void* W0, const void* b0, const void* W1,
    const void* b1, const void* W2, const void* b2, float* __restrict__ outp, int R,
    const int* __restrict__ flagp) {
    __shared__ __align__(16) float h1[64][64];
    __shared__ __align__(16) float h2[64][64];
    __shared__ float xs[64][DIN];
    const int bf = *flagp;
    const int tid = threadIdx.x;
    const int col = tid & 63;
    const int r0 = (tid >> 6) * 16;
    const long rb = (long)blockIdx.x * 64;

    for (int i = 0; i < 16; i++) {
        const int r = r0 + i;
        const long idx = rb + r;
        if (col < DIN) xs[r][col] = (idx < R) ? ldf(xin, idx * DIN + col, bf) : 0.f;
    }
    __syncthreads();

    float acc[16];
    {
        float b = ldf(b0, col, bf);
#pragma unroll
        for (int i = 0; i < 16; i++) acc[i] = b;
        for (int k = 0; k < DIN; k++) {
            float w = ldf(W0, (long)k * 64 + col, bf);
#pragma unroll
            for (int i = 0; i < 16; i++) acc[i] = fmaf(xs[r0 + i][k], w, acc[i]);
        }
#pragma unroll
        for (int i = 0; i < 16; i++) h1[r0 + i][col] = gelu_f(acc[i]);
    }
    __syncthreads();
    {
        float b = ldf(b1, col, bf);
#pragma unroll
        for (int i = 0; i < 16; i++) acc[i] = b;
        acc_part(acc, h1, r0, W1, 0, col, bf);
#pragma unroll
        for (int i = 0; i < 16; i++) h2[r0 + i][col] = gelu_f(acc[i]);
    }
    __syncthreads();
    {
        float b = ldf(b2, col, bf);
#pragma unroll
        for (int i = 0; i < 16; i++) acc[i] = b;
        acc_part(acc, h2, r0, W2, 0, col, bf);
    }
    for (int i = 0; i < 16; i++) {
        const long idx = rb + r0 + i;
        if (idx < R) outp[idx * 64 + col] = acc[i];
    }
}

// ---------- edge update (per step s) ----------
// new_e = MLP([e, n[snd], n[rcv], g]); recv += scatter(new_e); e = LN(e + new_e)
__global__ __launch_bounds__(256) void edge_update_kernel(
    float* __restrict__ e_lat, const float* __restrict__ n_lat,
    const int* __restrict__ senders, const int* __restrict__ receivers, const void* glob,
    const void* W0, const void* b0, const void* W1, const void* b1, const void* W2,
    const void* b2, const void* lnsc, const void* lnbi, float* __restrict__ recvbuf, int s,
    const int* __restrict__ flagp) {
    __shared__ __align__(16) float sm[4][64][64];  // 64 KB
    float (*xe)[64] = sm[0];
    float (*xns)[64] = sm[1];
    float (*xnr)[64] = sm[2];
    float (*h1)[64] = sm[3];
    float (*h2)[64] = sm[1];  // overlays xns (dead after layer 0)

    const int bf = *flagp;
    const int tid = threadIdx.x;
    const int col = tid & 63;
    const int r0 = (tid >> 6) * 16;
    const long rb = (long)blockIdx.x * 64;

    for (int i = 0; i < 16; i++) {
        const int r = r0 + i;
        const long eidx = rb + r;
        xe[r][col] = e_lat[eidx * 64 + col];
        const int sr = senders[eidx];
        const int rr = receivers[eidx];
        xns[r][col] = n_lat[(long)sr * 64 + col];
        xnr[r][col] = n_lat[(long)rr * 64 + col];
    }
    __syncthreads();

    float acc[16];
    {
        const long wb0 = (long)s * 194 * 64;
        const float b = ldf(b0, (long)s * 64 + col, bf);
#pragma unroll
        for (int i = 0; i < 16; i++) acc[i] = b;
        acc_part(acc, xe, r0, W0, wb0, col, bf);
        acc_part(acc, xns, r0, W0, wb0 + 64 * 64, col, bf);
        acc_part(acc, xnr, r0, W0, wb0 + 128 * 64, col, bf);
        const float g0 = ldf(glob, 0, bf), g1 = ldf(glob, 1, bf);
        const float w192 = ldf(W0, wb0 + (long)192 * 64 + col, bf);
        const float w193 = ldf(W0, wb0 + (long)193 * 64 + col, bf);
        const float gadd = g0 * w192 + g1 * w193;
#pragma unroll
        for (int i = 0; i < 16; i++) h1[r0 + i][col] = gelu_f(acc[i] + gadd);
    }
    __syncthreads();
    {
        const long wb1 = (long)s * 64 * 64;
        const float b = ldf(b1, (long)s * 64 + col, bf);
#pragma unroll
        for (int i = 0; i < 16; i++) acc[i] = b;
        acc_part(acc, h1, r0, W1, wb1, col, bf);
#pragma unroll
        for (int i = 0; i < 16; i++) h2[r0 + i][col] = gelu_f(acc[i]);
    }
    __syncthreads();
    {
        const long wb2 = (long)s * 64 * 64;
        const float b = ldf(b2, (long)s * 64 + col, bf);
#pragma unroll
        for (int i = 0; i < 16; i++) acc[i] = b;
        acc_part(acc, h2, r0, W2, wb2, col, bf);
    }
    const float lsc = ldf(lnsc, (long)s * 64 + col, bf);
    const float lbi = ldf(lnbi, (long)s * 64 + col, bf);
    for (int i = 0; i < 16; i++) {
        const int r = r0 + i;
        const long eidx = rb + r;
        const float ne = acc[i];
        atomicAdd(&recvbuf[(long)receivers[eidx] * 64 + col], ne);
        float u = xe[r][col] + ne;  // residual
        float ssum = u;
#pragma unroll
        for (int m = 32; m; m >>= 1) ssum += __shfl_xor(ssum, m, 64);
        const float mu = ssum * (1.0f / 64.0f);
        const float d = u - mu;
        float vv = d * d;
#pragma unroll
        for (int m = 32; m; m >>= 1) vv += __shfl_xor(vv, m, 64);
        e_lat[eidx * 64 + col] = d * rsqrtf(vv * (1.0f / 64.0f) + 1e-6f) * lsc + lbi;
    }
}

// ---------- node update (per step s) ----------
__global__ __launch_bounds__(256) void node_update_kernel(
    float* __restrict__ n_lat, float* __restrict__ recvbuf, const void* glob, const void* W0,
    const void* b0, const void* W1, const void* b1, const void* W2, const void* b2,
    const void* lnsc, const void* lnbi, int s, const int* __restrict__ flagp) {
    __shared__ __align__(16) float sm[3][64][64];  // 48 KB
    float (*xn)[64] = sm[0];
    float (*xr)[64] = sm[1];
    float (*h1)[64] = sm[2];
    float (*h2)[64] = sm[1];  // overlays xr

    const int bf = *flagp;
    const int tid = threadIdx.x;
    const int col = tid & 63;
    const int r0 = (tid >> 6) * 16;
    const long rb = (long)blockIdx.x * 64;

    for (int i = 0; i < 16; i++) {
        const int r = r0 + i;
        const long idx = rb + r;
        const bool v = idx < N_NODES;
        xn[r][col] = v ? n_lat[idx * 64 + col] : 0.f;
        xr[r][col] = v ? recvbuf[idx * 64 + col] : 0.f;
    }
    __syncthreads();

    float acc[16];
    {
        const long wb0 = (long)s * 130 * 64;
        const float b = ldf(b0, (long)s * 64 + col, bf);
#pragma unroll
        for (int i = 0; i < 16; i++) acc[i] = b;
        acc_part(acc, xn, r0, W0, wb0, col, bf);
        acc_part(acc, xr, r0, W0, wb0 + 64 * 64, col, bf);
        const float g0 = ldf(glob, 0, bf), g1 = ldf(glob, 1, bf);
        const float w128 = ldf(W0, wb0 + (long)128 * 64 + col, bf);
        const float w129 = ldf(W0, wb0 + (long)129 * 64 + col, bf);
        const float gadd = g0 * w128 + g1 * w129;
#pragma unroll
        for (int i = 0; i < 16; i++) h1[r0 + i][col] = gelu_f(acc[i] + gadd);
    }
    __syncthreads();
    {
        const long wb1 = (long)s * 64 * 64;
        const float b = ldf(b1, (long)s * 64 + col, bf);
#pragma unroll
        for (int i = 0; i < 16; i++) acc[i] = b;
        acc_part(acc, h1, r0, W1, wb1, col, bf);
#pragma unroll
        for (int i = 0; i < 16; i++) h2[r0 + i][col] = gelu_f(acc[i]);
    }
    __syncthreads();
    {
        const long wb2 = (long)s * 64 * 64;
        const float b = ldf(b2, (long)s * 64 + col, bf);
#pragma unroll
        for (int i = 0; i < 16; i++) acc[i] = b;
        acc_part(acc, h2, r0, W2, wb2, col, bf);
    }
    const float lsc = ldf(lnsc, (long)s * 64 + col, bf);
    const float lbi = ldf(lnbi, (long)s * 64 + col, bf);
    for (int i = 0; i < 16; i++) {
        const int r = r0 + i;
        const long idx = rb + r;
        float u = xn[r][col] + acc[i];
        float ssum = u;
#pragma unroll
        for (int m = 32; m; m >>= 1) ssum += __shfl_xor(ssum, m, 64);
        const float mu = ssum * (1.0f / 64.0f);
        const float d = u - mu;
        float vv = d * d;
#pragma unroll
        for (int m = 32; m; m >>= 1) vv += __shfl_xor(vv, m, 64);
        if (idx < N_NODES) {
            n_lat[idx * 64 + col] = d * rsqrtf(vv * (1.0f / 64.0f) + 1e-6f) * lsc + lbi;
            recvbuf[idx * 64 + col] = 0.f;  // ready for next step's atomics
        }
    }
}

// ---------- decoder: n_lat [N,64] -> MLP(64,64,64,3) -> out [N,3] ----------
__global__ __launch_bounds__(256) void decoder_kernel(
    const float* __restrict__ n_lat, const void* W0, const void* b0, const void* W1,
    const void* b1, const void* W2, const void* b2, void* __restrict__ outp,
    const int* __restrict__ flagp) {
    __shared__ __align__(16) float sm[2][64][64];  // 32 KB
    float (*xn)[64] = sm[0];
    float (*h1)[64] = sm[1];
    float (*h2)[64] = sm[0];  // overlays xn (dead after layer 0)

    const int bf = *flagp;
    const int tid = threadIdx.x;
    const int col = tid & 63;
    const int r0 = (tid >> 6) * 16;
    const long rb = (long)blockIdx.x * 64;

    for (int i = 0; i < 16; i++) {
        const int r = r0 + i;
        const long idx = rb + r;
        xn[r][col] = (idx < N_NODES) ? n_lat[idx * 64 + col] : 0.f;
    }
    __syncthreads();

    float acc[16];
    {
        const float b = ldf(b0, col, bf);
#pragma unroll
        for (int i = 0; i < 16; i++) acc[i] = b;
        acc_part(acc, xn, r0, W0, 0, col, bf);
#pragma unroll
        for (int i = 0; i < 16; i++) h1[r0 + i][col] = gelu_f(acc[i]);
    }
    __syncthreads();
    {
        const float b = ldf(b1, col, bf);
#pragma unroll
        for (int i = 0; i < 16; i++) acc[i] = b;
        acc_part(acc, h1, r0, W1, 0, col, bf);
#pragma unroll
        for (int i = 0; i < 16; i++) h2[r0 + i][col] = gelu_f(acc[i]);
    }
    __syncthreads();
    if (col < 3) {
        const float b = ldf(b2, col, bf);
#pragma unroll
        for (int i = 0; i < 16; i++) acc[i] = b;
        for (int k = 0; k < 64; k++) {
            float w = ldf(W2, (long)k * 3 + col, bf);
#pragma unroll
            for (int i = 0; i < 16; i++) acc[i] = fmaf(h2[r0 + i][k], w, acc[i]);
        }
        for (int i = 0; i < 16; i++) {
            const long idx = rb + r0 + i;
            if (idx < N_NODES) {
                if (bf)
                    ((unsigned short*)outp)[idx * 3 + col] = f2bf(acc[i]);
                else
                    ((float*)outp)[idx * 3 + col] = acc[i];
            }
        }
    }
}

// ---------- launch ----------
extern "C" void kernel_launch(void* const* d_in, const int* in_sizes, int n_in, void* d_out,
                              int out_size, void* d_ws, size_t ws_size, hipStream_t stream) {
    const void* nodes = d_in[0];
    const void* edges = d_in[1];
    const void* glob = d_in[2];
    const void *enW0 = d_in[3], *enb0 = d_in[4], *enW1 = d_in[5], *enb1 = d_in[6],
               *enW2 = d_in[7], *enb2 = d_in[8];
    const void *eeW0 = d_in[9], *eeb0 = d_in[10], *eeW1 = d_in[11], *eeb1 = d_in[12],
               *eeW2 = d_in[13], *eeb2 = d_in[14];
    const void *eW0 = d_in[15], *eb0 = d_in[16], *eW1 = d_in[17], *eb1 = d_in[18],
               *eW2 = d_in[19], *eb2 = d_in[20];
    const void *nW0 = d_in[21], *nb0 = d_in[22], *nW1 = d_in[23], *nb1 = d_in[24],
               *nW2 = d_in[25], *nb2 = d_in[26];
    const void *lnns = d_in[27], *lnnb = d_in[28], *lnes = d_in[29], *lneb = d_in[30];
    const void *dW0 = d_in[31], *db0 = d_in[32], *dW1 = d_in[33], *db1 = d_in[34],
               *dW2 = d_in[35], *db2 = d_in[36];
    const int* senders = (const int*)d_in[37];
    const int* receivers = (const int*)d_in[38];

    // workspace layout (fp32): n_lat | e_lat | recv | flag  (~230.4 MB)
    float* n_lat = (float*)d_ws;
    float* e_lat = n_lat + (size_t)N_NODES * 64;
    float* recvb = e_lat + (size_t)N_EDGES * 64;
    int* flag = (int*)(recvb + (size_t)N_NODES * 64);

    detect_kernel<<<1, 64, 0, stream>>>(lnns, flag);
    hipMemsetAsync(recvb, 0, (size_t)N_NODES * 64 * sizeof(float), stream);

    embed_kernel<7><<<(N_NODES + 63) / 64, 256, 0, stream>>>(nodes, enW0, enb0, enW1, enb1,
                                                             enW2, enb2, n_lat, N_NODES, flag);
    embed_kernel<4><<<N_EDGES / 64, 256, 0, stream>>>(edges, eeW0, eeb0, eeW1, eeb1, eeW2,
                                                      eeb2, e_lat, N_EDGES, flag);
    for (int s = 0; s < NSTEPS; s++) {
        edge_update_kernel<<<N_EDGES / 64, 256, 0, stream>>>(
            e_lat, n_lat, senders, receivers, glob, eW0, eb0, eW1, eb1, eW2, eb2, lnes, lneb,
            recvb, s, flag);
        node_update_kernel<<<(N_NODES + 63) / 64, 256, 0, stream>>>(
            n_lat, recvb, glob, nW0, nb0, nW1, nb1, nW2, nb2, lnns, lnnb, s, flag);
    }
    decoder_kernel<<<(N_NODES + 63) / 64, 256, 0, stream>>>(n_lat, dW0, db0, dW1, db1, dW2,
                                                            db2, d_out, flag);
}

// Round 2
// 1555.230 us; speedup vs baseline: 3.6623x; 3.6623x over previous
//
#include <hip/hip_runtime.h>

#define N_NODES 50000
#define N_EDGES 800000
#define NSTEPS 3

typedef __attribute__((ext_vector_type(8))) short bf16x8;
typedef __attribute__((ext_vector_type(4))) float f32x4;

// ---------- helpers ----------

__device__ __forceinline__ float ldf(const void* p, long i, int bf) {
    if (bf) {
        unsigned int u = ((const unsigned short*)p)[i];
        u <<= 16;
        return __uint_as_float(u);
    }
    return ((const float*)p)[i];
}

__device__ __forceinline__ unsigned short f2bf(float f) {
    unsigned int u = __float_as_uint(f);
    u = u + 0x7FFFu + ((u >> 16) & 1u);  // RNE
    return (unsigned short)(u >> 16);
}

__device__ __forceinline__ float bf2f(unsigned short u) {
    return __uint_as_float(((unsigned int)u) << 16);
}

// jax.nn.gelu default (approximate=True, tanh form)
__device__ __forceinline__ float gelu_f(float x) {
    float y = 1.5957691216057308f * (x + 0.044715f * x * x * x);
    float e = __expf(y);
    float t = 1.0f - 2.0f / (e + 1.0f);
    return 0.5f * x * (1.0f + t);
}

// acc[i] += sum_k xs[r0+i][k] * W[wbase + k*64 + col]   (fp32 path, non-edge kernels)
__device__ __forceinline__ void acc_part(float acc[16], const float (*xs)[64], int r0,
                                         const void* W, long wbase, int col, int bf) {
    for (int k = 0; k < 64; k += 4) {
        float wa = ldf(W, wbase + (long)(k + 0) * 64 + col, bf);
        float wb = ldf(W, wbase + (long)(k + 1) * 64 + col, bf);
        float wc = ldf(W, wbase + (long)(k + 2) * 64 + col, bf);
        float wd = ldf(W, wbase + (long)(k + 3) * 64 + col, bf);
#pragma unroll
        for (int i = 0; i < 16; i++) {
            const float4 x = *(const float4*)&xs[r0 + i][k];
            acc[i] = fmaf(x.x, wa, fmaf(x.y, wb, fmaf(x.z, wc, fmaf(x.w, wd, acc[i]))));
        }
    }
}

// ---------- dtype detect ----------
__global__ void detect_kernel(const void* probe, int* flag) {
    if (threadIdx.x == 0 && blockIdx.x == 0) {
        unsigned int w = *(const unsigned int*)probe;
        *flag = (w == 0x3F803F80u) ? 1 : 0;
    }
}

// ---------- weight prep: edge-MLP weights -> MFMA B-fragment order (bf16) ----------
// B-frag for 16x16x32: lane holds B[k = c*32 + (lane>>4)*8 + j][n = t*16 + (lane&15)], j=0..7
// Wb layout: [(s*C + c)*4 + t] blocks of 512 elements, element = lane*8 + j.
__global__ void prep_kernel(const void* eW0, const void* eb0, const void* glob,
                            const void* eW1, const void* eW2, unsigned short* Wb0,
                            unsigned short* Wb1, unsigned short* Wb2, float* b0eff,
                            const int* __restrict__ flagp) {
    const int bf = *flagp;
    int i = blockIdx.x * 256 + threadIdx.x;
    if (i < 36864) {  // W0: 3 steps x 6 kchunks x 4 coltiles x 512
        int j = i & 7, lane = (i >> 3) & 63, t = (i >> 9) & 3;
        int c = (i >> 11) % 6, s = i / 12288;
        int k = c * 32 + (lane >> 4) * 8 + j;
        int col = t * 16 + (lane & 15);
        Wb0[i] = f2bf(ldf(eW0, ((long)s * 194 + k) * 64 + col, bf));
    } else if (i < 36864 + 12288) {  // W1: 3 x 2 x 4 x 512
        int il = i - 36864;
        int j = il & 7, lane = (il >> 3) & 63, t = (il >> 9) & 3;
        int c = (il >> 11) % 2, s = il / 4096;
        int k = c * 32 + (lane >> 4) * 8 + j;
        int col = t * 16 + (lane & 15);
        Wb1[il] = f2bf(ldf(eW1, ((long)s * 64 + k) * 64 + col, bf));
    } else if (i < 36864 + 24576) {  // W2
        int il = i - 36864 - 12288;
        int j = il & 7, lane = (il >> 3) & 63, t = (il >> 9) & 3;
        int c = (il >> 11) % 2, s = il / 4096;
        int k = c * 32 + (lane >> 4) * 8 + j;
        int col = t * 16 + (lane & 15);
        Wb2[il] = f2bf(ldf(eW2, ((long)s * 64 + k) * 64 + col, bf));
    } else if (i < 36864 + 24576 + 192) {  // b0eff = b0 + g0*W0[192] + g1*W0[193]
        int il = i - 36864 - 24576;
        int s = il / 64, col = il % 64;
        float g0 = ldf(glob, 0, bf), g1 = ldf(glob, 1, bf);
        b0eff[il] = ldf(eb0, (long)s * 64 + col, bf) +
                    g0 * ldf(eW0, ((long)s * 194 + 192) * 64 + col, bf) +
                    g1 * ldf(eW0, ((long)s * 194 + 193) * 64 + col, bf);
    }
}

// ---------- embedder: [R, DIN] -> MLP(DIN,64,64,64) ----------
template <int DIN>
__global__ __launch_bounds__(256) void embed_kernel(
    const void* __restrict__ xin, const void* W0, const void* b0, const void* W1,
    const void* b1, const void* W2, const void* b2, void* __restrict__ outp, int R,
    int out_bf, const int* __restrict__ flagp) {
    __shared__ __align__(16) float h1[64][64];
    __shared__ __align__(16) float h2[64][64];
    __shared__ float xs[64][DIN];
    const int bf = *flagp;
    const int tid = threadIdx.x;
    const int col = tid & 63;
    const int r0 = (tid >> 6) * 16;
    const long rb = (long)blockIdx.x * 64;

    for (int i = 0; i < 16; i++) {
        const int r = r0 + i;
        const long idx = rb + r;
        if (col < DIN) xs[r][col] = (idx < R) ? ldf(xin, idx * DIN + col, bf) : 0.f;
    }
    __syncthreads();

    float acc[16];
    {
        float b = ldf(b0, col, bf);
#pragma unroll
        for (int i = 0; i < 16; i++) acc[i] = b;
        for (int k = 0; k < DIN; k++) {
            float w = ldf(W0, (long)k * 64 + col, bf);
#pragma unroll
            for (int i = 0; i < 16; i++) acc[i] = fmaf(xs[r0 + i][k], w, acc[i]);
        }
#pragma unroll
        for (int i = 0; i < 16; i++) h1[r0 + i][col] = gelu_f(acc[i]);
    }
    __syncthreads();
    {
        float b = ldf(b1, col, bf);
#pragma unroll
        for (int i = 0; i < 16; i++) acc[i] = b;
        acc_part(acc, h1, r0, W1, 0, col, bf);
#pragma unroll
        for (int i = 0; i < 16; i++) h2[r0 + i][col] = gelu_f(acc[i]);
    }
    __syncthreads();
    {
        float b = ldf(b2, col, bf);
#pragma unroll
        for (int i = 0; i < 16; i++) acc[i] = b;
        acc_part(acc, h2, r0, W2, 0, col, bf);
    }
    for (int i = 0; i < 16; i++) {
        const long idx = rb + r0 + i;
        if (idx < R) {
            if (out_bf)
                ((unsigned short*)outp)[idx * 64 + col] = f2bf(acc[i]);
            else
                ((float*)outp)[idx * 64 + col] = acc[i];
        }
    }
}

// ---------- edge update, MFMA version ----------
// LDS: Xs [64][200] bf16 (k: 0-63=e, 64-127=n[snd], 128-191=n[rcv]), h1/h2 [64][72] bf16.
// Each wave owns rows 16w..16w+15 end-to-end -> single __syncthreads after staging.
#define XS 200
#define HS 72
__global__ __launch_bounds__(256) void edge_update_mfma(
    unsigned short* __restrict__ e_lat, const float* __restrict__ n_lat,
    const int* __restrict__ senders, const int* __restrict__ receivers,
    const unsigned short* __restrict__ Wb0, const unsigned short* __restrict__ Wb1,
    const unsigned short* __restrict__ Wb2, const float* __restrict__ b0eff,
    const void* b1, const void* b2, const void* lnsc, const void* lnbi,
    float* __restrict__ recvbuf, int s, const int* __restrict__ flagp) {
    __shared__ __align__(16) unsigned short Xs[64 * XS];  // 25600 B
    __shared__ __align__(16) unsigned short h1[64 * HS];  // 9216 B
    __shared__ __align__(16) unsigned short h2[64 * HS];  // 9216 B

    const int bf = *flagp;
    const int tid = threadIdx.x;
    const long rb = (long)blockIdx.x * 64;

    // ---- stage e (bf16 copy) ----
    for (int c = tid; c < 512; c += 256) {
        int r = c >> 3, o = c & 7;
        *(uint4*)&Xs[r * XS + o * 8] = ((const uint4*)(e_lat + (rb + r) * 64))[o];
    }
    // ---- gather + convert n[senders], n[receivers] ----
    for (int c = tid; c < 1024; c += 256) {
        int part = c >> 9, r = (c >> 3) & 63, o = c & 7;
        long node = part ? receivers[rb + r] : senders[rb + r];
        const float4* src = (const float4*)(n_lat + node * 64 + o * 8);
        float4 x0 = src[0], x1 = src[1];
        unsigned short u[8] = {f2bf(x0.x), f2bf(x0.y), f2bf(x0.z), f2bf(x0.w),
                               f2bf(x1.x), f2bf(x1.y), f2bf(x1.z), f2bf(x1.w)};
        *(uint4*)&Xs[r * XS + 64 + part * 64 + o * 8] = *(uint4*)u;
    }
    __syncthreads();

    const int lane = tid & 63;
    const int w = tid >> 6;
    const int q = lane >> 4;
    const int l15 = lane & 15;
    const int arow = 16 * w + l15;
    const int aoff = q * 8;

    f32x4 acc0 = {0.f, 0.f, 0.f, 0.f}, acc1 = acc0, acc2 = acc0, acc3 = acc0;

    // ---- layer 0: K=192 (6 chunks) ----
    {
        const unsigned short* B = Wb0 + (long)s * 6 * 4 * 512 + lane * 8;
#pragma unroll
        for (int c = 0; c < 6; c++) {
            bf16x8 a = *(const bf16x8*)&Xs[arow * XS + c * 32 + aoff];
            const unsigned short* bb = B + c * 2048;
            acc0 = __builtin_amdgcn_mfma_f32_16x16x32_bf16(a, *(const bf16x8*)(bb), acc0, 0, 0, 0);
            acc1 = __builtin_amdgcn_mfma_f32_16x16x32_bf16(a, *(const bf16x8*)(bb + 512), acc1, 0, 0, 0);
            acc2 = __builtin_amdgcn_mfma_f32_16x16x32_bf16(a, *(const bf16x8*)(bb + 1024), acc2, 0, 0, 0);
            acc3 = __builtin_amdgcn_mfma_f32_16x16x32_bf16(a, *(const bf16x8*)(bb + 1536), acc3, 0, 0, 0);
        }
#pragma unroll
        for (int t = 0; t < 4; t++) {
            const int col = t * 16 + l15;
            const float b = b0eff[s * 64 + col];
            f32x4 a = t == 0 ? acc0 : t == 1 ? acc1 : t == 2 ? acc2 : acc3;
#pragma unroll
            for (int reg = 0; reg < 4; reg++)
                h1[(16 * w + q * 4 + reg) * HS + col] = f2bf(gelu_f(a[reg] + b));
        }
    }
    // ---- layer 1: K=64 (2 chunks) ----
    acc0 = (f32x4){0.f, 0.f, 0.f, 0.f}; acc1 = acc0; acc2 = acc0; acc3 = acc0;
    {
        const unsigned short* B = Wb1 + (long)s * 2 * 4 * 512 + lane * 8;
#pragma unroll
        for (int c = 0; c < 2; c++) {
            bf16x8 a = *(const bf16x8*)&h1[arow * HS + c * 32 + aoff];
            const unsigned short* bb = B + c * 2048;
            acc0 = __builtin_amdgcn_mfma_f32_16x16x32_bf16(a, *(const bf16x8*)(bb), acc0, 0, 0, 0);
            acc1 = __builtin_amdgcn_mfma_f32_16x16x32_bf16(a, *(const bf16x8*)(bb + 512), acc1, 0, 0, 0);
            acc2 = __builtin_amdgcn_mfma_f32_16x16x32_bf16(a, *(const bf16x8*)(bb + 1024), acc2, 0, 0, 0);
            acc3 = __builtin_amdgcn_mfma_f32_16x16x32_bf16(a, *(const bf16x8*)(bb + 1536), acc3, 0, 0, 0);
        }
#pragma unroll
        for (int t = 0; t < 4; t++) {
            const int col = t * 16 + l15;
            const float b = ldf(b1, (long)s * 64 + col, bf);
            f32x4 a = t == 0 ? acc0 : t == 1 ? acc1 : t == 2 ? acc2 : acc3;
#pragma unroll
            for (int reg = 0; reg < 4; reg++)
                h2[(16 * w + q * 4 + reg) * HS + col] = f2bf(gelu_f(a[reg] + b));
        }
    }
    // ---- layer 2: K=64 (2 chunks) ----
    acc0 = (f32x4){0.f, 0.f, 0.f, 0.f}; acc1 = acc0; acc2 = acc0; acc3 = acc0;
    {
        const unsigned short* B = Wb2 + (long)s * 2 * 4 * 512 + lane * 8;
#pragma unroll
        for (int c = 0; c < 2; c++) {
            bf16x8 a = *(const bf16x8*)&h2[arow * HS + c * 32 + aoff];
            const unsigned short* bb = B + c * 2048;
            acc0 = __builtin_amdgcn_mfma_f32_16x16x32_bf16(a, *(const bf16x8*)(bb), acc0, 0, 0, 0);
            acc1 = __builtin_amdgcn_mfma_f32_16x16x32_bf16(a, *(const bf16x8*)(bb + 512), acc1, 0, 0, 0);
            acc2 = __builtin_amdgcn_mfma_f32_16x16x32_bf16(a, *(const bf16x8*)(bb + 1024), acc2, 0, 0, 0);
            acc3 = __builtin_amdgcn_mfma_f32_16x16x32_bf16(a, *(const bf16x8*)(bb + 1536), acc3, 0, 0, 0);
        }
    }
    // ---- epilogue: scatter-add, residual, LayerNorm, store bf16 ----
    float fin[4][4];  // [reg][t]
    {
        f32x4 a[4] = {acc0, acc1, acc2, acc3};
#pragma unroll
        for (int t = 0; t < 4; t++) {
            const float b = ldf(b2, (long)s * 64 + t * 16 + l15, bf);
#pragma unroll
            for (int reg = 0; reg < 4; reg++) fin[reg][t] = a[t][reg] + b;
        }
    }
    float lsc[4], lbi[4];
#pragma unroll
    for (int t = 0; t < 4; t++) {
        lsc[t] = ldf(lnsc, (long)s * 64 + t * 16 + l15, bf);
        lbi[t] = ldf(lnbi, (long)s * 64 + t * 16 + l15, bf);
    }
#pragma unroll
    for (int reg = 0; reg < 4; reg++) {
        const int rowl = 16 * w + q * 4 + reg;
        const long eidx = rb + rowl;
        const int rcv = receivers[eidx];
        float u[4], ssum = 0.f;
#pragma unroll
        for (int t = 0; t < 4; t++) {
            const float v = fin[reg][t];
            atomicAdd(&recvbuf[(long)rcv * 64 + t * 16 + l15], v);
            u[t] = bf2f(Xs[rowl * XS + t * 16 + l15]) + v;
            ssum += u[t];
        }
#pragma unroll
        for (int m = 1; m < 16; m <<= 1) ssum += __shfl_xor(ssum, m, 64);
        const float mu = ssum * (1.0f / 64.0f);
        float d[4], vv = 0.f;
#pragma unroll
        for (int t = 0; t < 4; t++) { d[t] = u[t] - mu; vv += d[t] * d[t]; }
#pragma unroll
        for (int m = 1; m < 16; m <<= 1) vv += __shfl_xor(vv, m, 64);
        const float rs = rsqrtf(vv * (1.0f / 64.0f) + 1e-6f);
#pragma unroll
        for (int t = 0; t < 4; t++)
            e_lat[eidx * 64 + t * 16 + l15] = f2bf(d[t] * rs * lsc[t] + lbi[t]);
    }
}

// ---------- node update (fp32, unchanged) ----------
__global__ __launch_bounds__(256) void node_update_kernel(
    float* __restrict__ n_lat, float* __restrict__ recvbuf, const void* glob, const void* W0,
    const void* b0, const void* W1, const void* b1, const void* W2, const void* b2,
    const void* lnsc, const void* lnbi, int s, const int* __restrict__ flagp) {
    __shared__ __align__(16) float sm[3][64][64];
    float (*xn)[64] = sm[0];
    float (*xr)[64] = sm[1];
    float (*h1)[64] = sm[2];
    float (*h2)[64] = sm[1];

    const int bf = *flagp;
    const int tid = threadIdx.x;
    const int col = tid & 63;
    const int r0 = (tid >> 6) * 16;
    const long rb = (long)blockIdx.x * 64;

    for (int i = 0; i < 16; i++) {
        const int r = r0 + i;
        const long idx = rb + r;
        const bool v = idx < N_NODES;
        xn[r][col] = v ? n_lat[idx * 64 + col] : 0.f;
        xr[r][col] = v ? recvbuf[idx * 64 + col] : 0.f;
    }
    __syncthreads();

    float acc[16];
    {
        const long wb0 = (long)s * 130 * 64;
        const float b = ldf(b0, (long)s * 64 + col, bf);
#pragma unroll
        for (int i = 0; i < 16; i++) acc[i] = b;
        acc_part(acc, xn, r0, W0, wb0, col, bf);
        acc_part(acc, xr, r0, W0, wb0 + 64 * 64, col, bf);
        const float g0 = ldf(glob, 0, bf), g1 = ldf(glob, 1, bf);
        const float w128 = ldf(W0, wb0 + (long)128 * 64 + col, bf);
        const float w129 = ldf(W0, wb0 + (long)129 * 64 + col, bf);
        const float gadd = g0 * w128 + g1 * w129;
#pragma unroll
        for (int i = 0; i < 16; i++) h1[r0 + i][col] = gelu_f(acc[i] + gadd);
    }
    __syncthreads();
    {
        const long wb1 = (long)s * 64 * 64;
        const float b = ldf(b1, (long)s * 64 + col, bf);
#pragma unroll
        for (int i = 0; i < 16; i++) acc[i] = b;
        acc_part(acc, h1, r0, W1, wb1, col, bf);
#pragma unroll
        for (int i = 0; i < 16; i++) h2[r0 + i][col] = gelu_f(acc[i]);
    }
    __syncthreads();
    {
        const long wb2 = (long)s * 64 * 64;
        const float b = ldf(b2, (long)s * 64 + col, bf);
#pragma unroll
        for (int i = 0; i < 16; i++) acc[i] = b;
        acc_part(acc, h2, r0, W2, wb2, col, bf);
    }
    const float lsc = ldf(lnsc, (long)s * 64 + col, bf);
    const float lbi = ldf(lnbi, (long)s * 64 + col, bf);
    for (int i = 0; i < 16; i++) {
        const int r = r0 + i;
        const long idx = rb + r;
        float u = xn[r][col] + acc[i];
        float ssum = u;
#pragma unroll
        for (int m = 32; m; m >>= 1) ssum += __shfl_xor(ssum, m, 64);
        const float mu = ssum * (1.0f / 64.0f);
        const float d = u - mu;
        float vv = d * d;
#pragma unroll
        for (int m = 32; m; m >>= 1) vv += __shfl_xor(vv, m, 64);
        if (idx < N_NODES) {
            n_lat[idx * 64 + col] = d * rsqrtf(vv * (1.0f / 64.0f) + 1e-6f) * lsc + lbi;
            recvbuf[idx * 64 + col] = 0.f;
        }
    }
}

// ---------- decoder (fp32, unchanged) ----------
__global__ __launch_bounds__(256) void decoder_kernel(
    const float* __restrict__ n_lat, const void* W0, const void* b0, const void* W1,
    const void* b1, const void* W2, const void* b2, void* __restrict__ outp,
    const int* __restrict__ flagp) {
    __shared__ __align__(16) float sm[2][64][64];
    float (*xn)[64] = sm[0];
    float (*h1)[64] = sm[1];
    float (*h2)[64] = sm[0];

    const int bf = *flagp;
    const int tid = threadIdx.x;
    const int col = tid & 63;
    const int r0 = (tid >> 6) * 16;
    const long rb = (long)blockIdx.x * 64;

    for (int i = 0; i < 16; i++) {
        const int r = r0 + i;
        const long idx = rb + r;
        xn[r][col] = (idx < N_NODES) ? n_lat[idx * 64 + col] : 0.f;
    }
    __syncthreads();

    float acc[16];
    {
        const float b = ldf(b0, col, bf);
#pragma unroll
        for (int i = 0; i < 16; i++) acc[i] = b;
        acc_part(acc, xn, r0, W0, 0, col, bf);
#pragma unroll
        for (int i = 0; i < 16; i++) h1[r0 + i][col] = gelu_f(acc[i]);
    }
    __syncthreads();
    {
        const float b = ldf(b1, col, bf);
#pragma unroll
        for (int i = 0; i < 16; i++) acc[i] = b;
        acc_part(acc, h1, r0, W1, 0, col, bf);
#pragma unroll
        for (int i = 0; i < 16; i++) h2[r0 + i][col] = gelu_f(acc[i]);
    }
    __syncthreads();
    if (col < 3) {
        const float b = ldf(b2, col, bf);
#pragma unroll
        for (int i = 0; i < 16; i++) acc[i] = b;
        for (int k = 0; k < 64; k++) {
            float w = ldf(W2, (long)k * 3 + col, bf);
#pragma unroll
            for (int i = 0; i < 16; i++) acc[i] = fmaf(h2[r0 + i][k], w, acc[i]);
        }
        for (int i = 0; i < 16; i++) {
            const long idx = rb + r0 + i;
            if (idx < N_NODES) {
                if (bf)
                    ((unsigned short*)outp)[idx * 3 + col] = f2bf(acc[i]);
                else
                    ((float*)outp)[idx * 3 + col] = acc[i];
            }
        }
    }
}

// ---------- launch ----------
extern "C" void kernel_launch(void* const* d_in, const int* in_sizes, int n_in, void* d_out,
                              int out_size, void* d_ws, size_t ws_size, hipStream_t stream) {
    const void* nodes = d_in[0];
    const void* edges = d_in[1];
    const void* glob = d_in[2];
    const void *enW0 = d_in[3], *enb0 = d_in[4], *enW1 = d_in[5], *enb1 = d_in[6],
               *enW2 = d_in[7], *enb2 = d_in[8];
    const void *eeW0 = d_in[9], *eeb0 = d_in[10], *eeW1 = d_in[11], *eeb1 = d_in[12],
               *eeW2 = d_in[13], *eeb2 = d_in[14];
    const void *eW0 = d_in[15], *eb0 = d_in[16], *eW1 = d_in[17], *eb1 = d_in[18],
               *eW2 = d_in[19], *eb2 = d_in[20];
    const void *nW0 = d_in[21], *nb0 = d_in[22], *nW1 = d_in[23], *nb1 = d_in[24],
               *nW2 = d_in[25], *nb2 = d_in[26];
    const void *lnns = d_in[27], *lnnb = d_in[28], *lnes = d_in[29], *lneb = d_in[30];
    const void *dW0 = d_in[31], *db0 = d_in[32], *dW1 = d_in[33], *db1 = d_in[34],
               *dW2 = d_in[35], *db2 = d_in[36];
    const int* senders = (const int*)d_in[37];
    const int* receivers = (const int*)d_in[38];

    // workspace layout
    float* n_lat = (float*)d_ws;                     // 3,200,000 f32
    float* recvb = n_lat + 3200000;                  // 3,200,000 f32
    float* b0eff = recvb + 3200000;                  // 192 f32
    int* flag = (int*)(b0eff + 192);                 // few ints, pad to 256
    unsigned short* e_lat = (unsigned short*)(b0eff + 256);  // 51,200,000 bf16
    unsigned short* Wb0 = e_lat + 51200000;          // 36,864
    unsigned short* Wb1 = Wb0 + 36864;               // 12,288
    unsigned short* Wb2 = Wb1 + 12288;               // 12,288

    detect_kernel<<<1, 64, 0, stream>>>(lnns, flag);
    prep_kernel<<<(36864 + 24576 + 192 + 255) / 256, 256, 0, stream>>>(
        eW0, eb0, glob, eW1, eW2, Wb0, Wb1, Wb2, b0eff, flag);
    hipMemsetAsync(recvb, 0, (size_t)N_NODES * 64 * sizeof(float), stream);

    embed_kernel<7><<<(N_NODES + 63) / 64, 256, 0, stream>>>(
        nodes, enW0, enb0, enW1, enb1, enW2, enb2, n_lat, N_NODES, 0, flag);
    embed_kernel<4><<<N_EDGES / 64, 256, 0, stream>>>(
        edges, eeW0, eeb0, eeW1, eeb1, eeW2, eeb2, e_lat, N_EDGES, 1, flag);
    for (int s = 0; s < NSTEPS; s++) {
        edge_update_mfma<<<N_EDGES / 64, 256, 0, stream>>>(
            e_lat, n_lat, senders, receivers, Wb0, Wb1, Wb2, b0eff, eb1, eb2, lnes, lneb,
            recvb, s, flag);
        node_update_kernel<<<(N_NODES + 63) / 64, 256, 0, stream>>>(
            n_lat, recvb, glob, nW0, nb0, nW1, nb1, nW2, nb2, lnns, lnnb, s, flag);
    }
    decoder_kernel<<<(N_NODES + 63) / 64, 256, 0, stream>>>(n_lat, dW0, db0, dW1, db1, dW2,
                                                            db2, d_out, flag);
}

// Round 3
// 1018.465 us; speedup vs baseline: 5.5925x; 1.5270x over previous
//
#include <hip/hip_runtime.h>

#define N_NODES 50000
#define N_EDGES 800000
#define NSTEPS 3

typedef __attribute__((ext_vector_type(8))) short bf16x8;
typedef __attribute__((ext_vector_type(4))) float f32x4;

// ---------- helpers ----------

__device__ __forceinline__ float ldf(const void* p, long i, int bf) {
    if (bf) {
        unsigned int u = ((const unsigned short*)p)[i];
        u <<= 16;
        return __uint_as_float(u);
    }
    return ((const float*)p)[i];
}

__device__ __forceinline__ unsigned short f2bf(float f) {
    unsigned int u = __float_as_uint(f);
    u = u + 0x7FFFu + ((u >> 16) & 1u);  // RNE
    return (unsigned short)(u >> 16);
}

__device__ __forceinline__ float bf2f(unsigned short u) {
    return __uint_as_float(((unsigned int)u) << 16);
}

// jax.nn.gelu default (approximate=True, tanh form)
__device__ __forceinline__ float gelu_f(float x) {
    float y = 1.5957691216057308f * (x + 0.044715f * x * x * x);
    float e = __expf(y);
    float t = 1.0f - 2.0f / (e + 1.0f);
    return 0.5f * x * (1.0f + t);
}

__device__ __forceinline__ void zero4(f32x4 a[4]) {
#pragma unroll
    for (int t = 0; t < 4; t++) a[t] = (f32x4){0.f, 0.f, 0.f, 0.f};
}

// one K=32 chunk against 4 column tiles
__device__ __forceinline__ void mfma_chunk(f32x4 acc[4], bf16x8 a, const unsigned short* bb) {
    acc[0] = __builtin_amdgcn_mfma_f32_16x16x32_bf16(a, *(const bf16x8*)(bb + 0), acc[0], 0, 0, 0);
    acc[1] = __builtin_amdgcn_mfma_f32_16x16x32_bf16(a, *(const bf16x8*)(bb + 512), acc[1], 0, 0, 0);
    acc[2] = __builtin_amdgcn_mfma_f32_16x16x32_bf16(a, *(const bf16x8*)(bb + 1024), acc[2], 0, 0, 0);
    acc[3] = __builtin_amdgcn_mfma_f32_16x16x32_bf16(a, *(const bf16x8*)(bb + 1536), acc[3], 0, 0, 0);
}

// ---------- dtype detect ----------
__global__ void detect_kernel(const void* probe, int* flag) {
    if (threadIdx.x == 0 && blockIdx.x == 0) {
        unsigned int w = *(const unsigned int*)probe;
        *flag = (w == 0x3F803F80u) ? 1 : 0;
    }
}

// ---------- fused weight prep ----------
// B-frag for 16x16x32: element i within a matrix: j=i&7, lane=(i>>3)&63, t=(i>>9)&3,
// c=(i>>11)%nch, s=i/(2048*nch); k=c*32+(lane>>4)*8+j; col=t*16+(lane&15).
struct PrepPtrs {
    const void* W[14];
    const void* eb0;
    const void* nb0;
    const void* glob;
};

#define PREP_WTOTAL 139264
__global__ void prep_all(PrepPtrs p, unsigned short* WbBase, float* b0eff_e, float* b0eff_n,
                         const int* __restrict__ flagp) {
    const int totals[14] = {36864, 12288, 12288, 24576, 12288, 12288, 2048,
                            4096,  4096,  2048,  4096,  4096,  4096,  4096};
    const int ksrc[14] = {192, 64, 64, 128, 64, 64, 7, 64, 64, 4, 64, 64, 64, 64};
    const int sstride[14] = {12416, 4096, 4096, 8320, 4096, 4096, 448,
                             4096,  4096, 256,  4096, 4096, 4096, 4096};
    const int nch[14] = {6, 2, 2, 4, 2, 2, 1, 2, 2, 1, 2, 2, 2, 2};

    const int bf = *flagp;
    int i = blockIdx.x * 256 + threadIdx.x;
    if (i < PREP_WTOTAL) {
        int e = 0, base = 0;
        while (i >= base + totals[e]) { base += totals[e]; e++; }
        int il = i - base;
        int j = il & 7, lane = (il >> 3) & 63, t = (il >> 9) & 3;
        int c = (il >> 11) % nch[e], s = il / (2048 * nch[e]);
        int k = c * 32 + (lane >> 4) * 8 + j;
        int col = t * 16 + (lane & 15);
        WbBase[i] = (k < ksrc[e]) ? f2bf(ldf(p.W[e], (long)s * sstride[e] + (long)k * 64 + col, bf))
                                  : (unsigned short)0;
    } else if (i < PREP_WTOTAL + 384) {
        int i2 = i - PREP_WTOTAL;
        float g0 = ldf(p.glob, 0, bf), g1 = ldf(p.glob, 1, bf);
        if (i2 < 192) {
            int s = i2 >> 6, col = i2 & 63;
            b0eff_e[i2] = ldf(p.eb0, i2, bf) + g0 * ldf(p.W[0], (long)s * 12416 + 192 * 64 + col, bf)
                                             + g1 * ldf(p.W[0], (long)s * 12416 + 193 * 64 + col, bf);
        } else {
            int il = i2 - 192;
            int s = il >> 6, col = il & 63;
            b0eff_n[il] = ldf(p.nb0, il, bf) + g0 * ldf(p.W[3], (long)s * 8320 + 128 * 64 + col, bf)
                                             + g1 * ldf(p.W[3], (long)s * 8320 + 129 * 64 + col, bf);
        }
    }
}

// ---------- embedder (MFMA): [R, DIN] -> MLP(DIN,64,64,64) ----------
template <int DIN, int OUT_BF>
__global__ __launch_bounds__(256) void embed_mfma(
    const void* __restrict__ xin, const unsigned short* __restrict__ Wb0, const void* b0,
    const unsigned short* __restrict__ Wb1, const void* b1,
    const unsigned short* __restrict__ Wb2, const void* b2, void* __restrict__ outp, int R,
    const int* __restrict__ flagp) {
    __shared__ __align__(16) unsigned short Xs[64 * 40];
    __shared__ __align__(16) unsigned short h1[64 * 72];
    __shared__ __align__(16) unsigned short h2[64 * 72];
    const int bf = *flagp;
    const int tid = threadIdx.x;
    const long rb = (long)blockIdx.x * 64;
    {
        int r = tid >> 2, seg = tid & 3;
        long idx = rb + r;
        unsigned short u[8];
#pragma unroll
        for (int j = 0; j < 8; j++) {
            int col = seg * 8 + j;
            u[j] = (col < DIN && idx < R) ? f2bf(ldf(xin, idx * DIN + col, bf)) : (unsigned short)0;
        }
        *(uint4*)&Xs[r * 40 + seg * 8] = *(uint4*)u;
    }
    __syncthreads();
    const int lane = tid & 63, w = tid >> 6, q = lane >> 4, l15 = lane & 15;
    const int arow = 16 * w + l15, aoff = q * 8;

    f32x4 acc[4];
    zero4(acc);
    {  // layer 0 (1 chunk, zero-padded K)
        bf16x8 a = *(const bf16x8*)&Xs[arow * 40 + aoff];
        mfma_chunk(acc, a, Wb0 + lane * 8);
#pragma unroll
        for (int t = 0; t < 4; t++) {
            int col = t * 16 + l15;
            float b = ldf(b0, col, bf);
#pragma unroll
            for (int reg = 0; reg < 4; reg++)
                h1[(16 * w + q * 4 + reg) * 72 + col] = f2bf(gelu_f(acc[t][reg] + b));
        }
    }
    zero4(acc);
    {  // layer 1
#pragma unroll
        for (int c = 0; c < 2; c++) {
            bf16x8 a = *(const bf16x8*)&h1[arow * 72 + c * 32 + aoff];
            mfma_chunk(acc, a, Wb1 + c * 2048 + lane * 8);
        }
#pragma unroll
        for (int t = 0; t < 4; t++) {
            int col = t * 16 + l15;
            float b = ldf(b1, col, bf);
#pragma unroll
            for (int reg = 0; reg < 4; reg++)
                h2[(16 * w + q * 4 + reg) * 72 + col] = f2bf(gelu_f(acc[t][reg] + b));
        }
    }
    zero4(acc);
    {  // layer 2
#pragma unroll
        for (int c = 0; c < 2; c++) {
            bf16x8 a = *(const bf16x8*)&h2[arow * 72 + c * 32 + aoff];
            mfma_chunk(acc, a, Wb2 + c * 2048 + lane * 8);
        }
    }
    if (OUT_BF) {
        // store via LDS (reuse h1) for contiguous uint4 global writes
#pragma unroll
        for (int t = 0; t < 4; t++) {
            int col = t * 16 + l15;
            float b = ldf(b2, col, bf);
#pragma unroll
            for (int reg = 0; reg < 4; reg++)
                h1[(16 * w + q * 4 + reg) * 72 + col] = f2bf(acc[t][reg] + b);
        }
        __syncthreads();
        for (int cc = tid; cc < 512; cc += 256) {
            int r = cc >> 3, seg = cc & 7;
            long idx = rb + r;
            if (idx < R)
                *(uint4*)&((unsigned short*)outp)[idx * 64 + seg * 8] =
                    *(const uint4*)&h1[r * 72 + seg * 8];
        }
    } else {
#pragma unroll
        for (int t = 0; t < 4; t++) {
            int col = t * 16 + l15;
            float b = ldf(b2, col, bf);
#pragma unroll
            for (int reg = 0; reg < 4; reg++) {
                long idx = rb + 16 * w + q * 4 + reg;
                if (idx < R) ((float*)outp)[idx * 64 + col] = acc[t][reg] + b;
            }
        }
    }
}

// ---------- edge update, MFMA (unchanged from R2) ----------
#define XS 200
#define HS 72
__global__ __launch_bounds__(256) void edge_update_mfma(
    unsigned short* __restrict__ e_lat, const float* __restrict__ n_lat,
    const int* __restrict__ senders, const int* __restrict__ receivers,
    const unsigned short* __restrict__ Wb0, const unsigned short* __restrict__ Wb1,
    const unsigned short* __restrict__ Wb2, const float* __restrict__ b0eff, const void* b1,
    const void* b2, const void* lnsc, const void* lnbi, float* __restrict__ recvbuf, int s,
    const int* __restrict__ flagp) {
    __shared__ __align__(16) unsigned short Xs[64 * XS];
    __shared__ __align__(16) unsigned short h1[64 * HS];
    __shared__ __align__(16) unsigned short h2[64 * HS];

    const int bf = *flagp;
    const int tid = threadIdx.x;
    const long rb = (long)blockIdx.x * 64;

    for (int c = tid; c < 512; c += 256) {
        int r = c >> 3, o = c & 7;
        *(uint4*)&Xs[r * XS + o * 8] = ((const uint4*)(e_lat + (rb + r) * 64))[o];
    }
    for (int c = tid; c < 1024; c += 256) {
        int part = c >> 9, r = (c >> 3) & 63, o = c & 7;
        long node = part ? receivers[rb + r] : senders[rb + r];
        const float4* src = (const float4*)(n_lat + node * 64 + o * 8);
        float4 x0 = src[0], x1 = src[1];
        unsigned short u[8] = {f2bf(x0.x), f2bf(x0.y), f2bf(x0.z), f2bf(x0.w),
                               f2bf(x1.x), f2bf(x1.y), f2bf(x1.z), f2bf(x1.w)};
        *(uint4*)&Xs[r * XS + 64 + part * 64 + o * 8] = *(uint4*)u;
    }
    __syncthreads();

    const int lane = tid & 63, w = tid >> 6, q = lane >> 4, l15 = lane & 15;
    const int arow = 16 * w + l15, aoff = q * 8;

    f32x4 acc[4];
    zero4(acc);
    {
        const unsigned short* B = Wb0 + (long)s * 6 * 2048 + lane * 8;
#pragma unroll
        for (int c = 0; c < 6; c++) {
            bf16x8 a = *(const bf16x8*)&Xs[arow * XS + c * 32 + aoff];
            mfma_chunk(acc, a, B + c * 2048);
        }
#pragma unroll
        for (int t = 0; t < 4; t++) {
            const int col = t * 16 + l15;
            const float b = b0eff[s * 64 + col];
#pragma unroll
            for (int reg = 0; reg < 4; reg++)
                h1[(16 * w + q * 4 + reg) * HS + col] = f2bf(gelu_f(acc[t][reg] + b));
        }
    }
    zero4(acc);
    {
        const unsigned short* B = Wb1 + (long)s * 2 * 2048 + lane * 8;
#pragma unroll
        for (int c = 0; c < 2; c++) {
            bf16x8 a = *(const bf16x8*)&h1[arow * HS + c * 32 + aoff];
            mfma_chunk(acc, a, B + c * 2048);
        }
#pragma unroll
        for (int t = 0; t < 4; t++) {
            const int col = t * 16 + l15;
            const float b = ldf(b1, (long)s * 64 + col, bf);
#pragma unroll
            for (int reg = 0; reg < 4; reg++)
                h2[(16 * w + q * 4 + reg) * HS + col] = f2bf(gelu_f(acc[t][reg] + b));
        }
    }
    zero4(acc);
    {
        const unsigned short* B = Wb2 + (long)s * 2 * 2048 + lane * 8;
#pragma unroll
        for (int c = 0; c < 2; c++) {
            bf16x8 a = *(const bf16x8*)&h2[arow * HS + c * 32 + aoff];
            mfma_chunk(acc, a, B + c * 2048);
        }
    }
    float fin[4][4];
#pragma unroll
    for (int t = 0; t < 4; t++) {
        const float b = ldf(b2, (long)s * 64 + t * 16 + l15, bf);
#pragma unroll
        for (int reg = 0; reg < 4; reg++) fin[reg][t] = acc[t][reg] + b;
    }
    float lsc[4], lbi[4];
#pragma unroll
    for (int t = 0; t < 4; t++) {
        lsc[t] = ldf(lnsc, (long)s * 64 + t * 16 + l15, bf);
        lbi[t] = ldf(lnbi, (long)s * 64 + t * 16 + l15, bf);
    }
#pragma unroll
    for (int reg = 0; reg < 4; reg++) {
        const int rowl = 16 * w + q * 4 + reg;
        const long eidx = rb + rowl;
        const int rcv = receivers[eidx];
        float u[4], ssum = 0.f;
#pragma unroll
        for (int t = 0; t < 4; t++) {
            const float v = fin[reg][t];
            atomicAdd(&recvbuf[(long)rcv * 64 + t * 16 + l15], v);
            u[t] = bf2f(Xs[rowl * XS + t * 16 + l15]) + v;
            ssum += u[t];
        }
#pragma unroll
        for (int m = 1; m < 16; m <<= 1) ssum += __shfl_xor(ssum, m, 64);
        const float mu = ssum * (1.0f / 64.0f);
        float d[4], vv = 0.f;
#pragma unroll
        for (int t = 0; t < 4; t++) { d[t] = u[t] - mu; vv += d[t] * d[t]; }
#pragma unroll
        for (int m = 1; m < 16; m <<= 1) vv += __shfl_xor(vv, m, 64);
        const float rs = rsqrtf(vv * (1.0f / 64.0f) + 1e-6f);
#pragma unroll
        for (int t = 0; t < 4; t++)
            e_lat[eidx * 64 + t * 16 + l15] = f2bf(d[t] * rs * lsc[t] + lbi[t]);
    }
}

// ---------- node update (MFMA) ----------
#define NXS 136
__global__ __launch_bounds__(256) void node_update_mfma(
    float* __restrict__ n_lat, float* __restrict__ recvbuf,
    const unsigned short* __restrict__ Wb0, const float* __restrict__ b0eff,
    const unsigned short* __restrict__ Wb1, const void* b1,
    const unsigned short* __restrict__ Wb2, const void* b2, const void* lnsc,
    const void* lnbi, int s, const int* __restrict__ flagp) {
    __shared__ __align__(16) unsigned short Xs[64 * NXS];
    __shared__ __align__(16) unsigned short h1[64 * 72];
    __shared__ __align__(16) unsigned short h2[64 * 72];
    const int bf = *flagp;
    const int tid = threadIdx.x;
    const long rb = (long)blockIdx.x * 64;

    for (int cc = tid; cc < 1024; cc += 256) {
        int r = cc >> 4, seg = cc & 15;
        long idx = rb + r;
        unsigned short u[8] = {0, 0, 0, 0, 0, 0, 0, 0};
        if (idx < N_NODES) {
            const float* src = (seg < 8) ? (n_lat + idx * 64 + seg * 8)
                                         : (recvbuf + idx * 64 + (seg - 8) * 8);
            float4 x0 = *(const float4*)src, x1 = *(const float4*)(src + 4);
            u[0] = f2bf(x0.x); u[1] = f2bf(x0.y); u[2] = f2bf(x0.z); u[3] = f2bf(x0.w);
            u[4] = f2bf(x1.x); u[5] = f2bf(x1.y); u[6] = f2bf(x1.z); u[7] = f2bf(x1.w);
        }
        *(uint4*)&Xs[r * NXS + (seg < 8 ? seg * 8 : 64 + (seg - 8) * 8)] = *(uint4*)u;
    }
    __syncthreads();

    const int lane = tid & 63, w = tid >> 6, q = lane >> 4, l15 = lane & 15;
    const int arow = 16 * w + l15, aoff = q * 8;

    f32x4 acc[4];
    zero4(acc);
    {  // layer 0: K=128 (glob folded into b0eff)
        const unsigned short* B = Wb0 + (long)s * 4 * 2048 + lane * 8;
#pragma unroll
        for (int c = 0; c < 4; c++) {
            bf16x8 a = *(const bf16x8*)&Xs[arow * NXS + c * 32 + aoff];
            mfma_chunk(acc, a, B + c * 2048);
        }
#pragma unroll
        for (int t = 0; t < 4; t++) {
            const int col = t * 16 + l15;
            const float b = b0eff[s * 64 + col];
#pragma unroll
            for (int reg = 0; reg < 4; reg++)
                h1[(16 * w + q * 4 + reg) * 72 + col] = f2bf(gelu_f(acc[t][reg] + b));
        }
    }
    zero4(acc);
    {
        const unsigned short* B = Wb1 + (long)s * 2 * 2048 + lane * 8;
#pragma unroll
        for (int c = 0; c < 2; c++) {
            bf16x8 a = *(const bf16x8*)&h1[arow * 72 + c * 32 + aoff];
            mfma_chunk(acc, a, B + c * 2048);
        }
#pragma unroll
        for (int t = 0; t < 4; t++) {
            const int col = t * 16 + l15;
            const float b = ldf(b1, (long)s * 64 + col, bf);
#pragma unroll
            for (int reg = 0; reg < 4; reg++)
                h2[(16 * w + q * 4 + reg) * 72 + col] = f2bf(gelu_f(acc[t][reg] + b));
        }
    }
    zero4(acc);
    {
        const unsigned short* B = Wb2 + (long)s * 2 * 2048 + lane * 8;
#pragma unroll
        for (int c = 0; c < 2; c++) {
            bf16x8 a = *(const bf16x8*)&h2[arow * 72 + c * 32 + aoff];
            mfma_chunk(acc, a, B + c * 2048);
        }
    }
    float b2v[4], lsc[4], lbi[4];
#pragma unroll
    for (int t = 0; t < 4; t++) {
        b2v[t] = ldf(b2, (long)s * 64 + t * 16 + l15, bf);
        lsc[t] = ldf(lnsc, (long)s * 64 + t * 16 + l15, bf);
        lbi[t] = ldf(lnbi, (long)s * 64 + t * 16 + l15, bf);
    }
#pragma unroll
    for (int reg = 0; reg < 4; reg++) {
        const int rowl = 16 * w + q * 4 + reg;
        const long idx = rb + rowl;
        const bool valid = idx < N_NODES;
        float u[4], ssum = 0.f;
#pragma unroll
        for (int t = 0; t < 4; t++) {
            const int col = t * 16 + l15;
            float xn = valid ? n_lat[idx * 64 + col] : 0.f;
            u[t] = xn + acc[t][reg] + b2v[t];
            ssum += u[t];
        }
#pragma unroll
        for (int m = 1; m < 16; m <<= 1) ssum += __shfl_xor(ssum, m, 64);
        const float mu = ssum * (1.0f / 64.0f);
        float d[4], vv = 0.f;
#pragma unroll
        for (int t = 0; t < 4; t++) { d[t] = u[t] - mu; vv += d[t] * d[t]; }
#pragma unroll
        for (int m = 1; m < 16; m <<= 1) vv += __shfl_xor(vv, m, 64);
        const float rs = rsqrtf(vv * (1.0f / 64.0f) + 1e-6f);
        if (valid) {
#pragma unroll
            for (int t = 0; t < 4; t++) {
                const int col = t * 16 + l15;
                n_lat[idx * 64 + col] = d[t] * rs * lsc[t] + lbi[t];
                recvbuf[idx * 64 + col] = 0.f;
            }
        }
    }
}

// ---------- decoder (MFMA layers 0-1, VALU final 64->3) ----------
__global__ __launch_bounds__(256) void decoder_mfma(
    const float* __restrict__ n_lat, const unsigned short* __restrict__ Wb0, const void* b0,
    const unsigned short* __restrict__ Wb1, const void* b1, const void* W2, const void* b2,
    void* __restrict__ outp, const int* __restrict__ flagp) {
    __shared__ __align__(16) unsigned short Xs[64 * 72];
    __shared__ __align__(16) unsigned short h1[64 * 72];
    __shared__ __align__(16) unsigned short h2[64 * 72];
    const int bf = *flagp;
    const int tid = threadIdx.x;
    const long rb = (long)blockIdx.x * 64;

    for (int cc = tid; cc < 512; cc += 256) {
        int r = cc >> 3, seg = cc & 7;
        long idx = rb + r;
        unsigned short u[8] = {0, 0, 0, 0, 0, 0, 0, 0};
        if (idx < N_NODES) {
            const float* src = n_lat + idx * 64 + seg * 8;
            float4 x0 = *(const float4*)src, x1 = *(const float4*)(src + 4);
            u[0] = f2bf(x0.x); u[1] = f2bf(x0.y); u[2] = f2bf(x0.z); u[3] = f2bf(x0.w);
            u[4] = f2bf(x1.x); u[5] = f2bf(x1.y); u[6] = f2bf(x1.z); u[7] = f2bf(x1.w);
        }
        *(uint4*)&Xs[r * 72 + seg * 8] = *(uint4*)u;
    }
    __syncthreads();

    const int lane = tid & 63, w = tid >> 6, q = lane >> 4, l15 = lane & 15;
    const int arow = 16 * w + l15, aoff = q * 8;

    f32x4 acc[4];
    zero4(acc);
    {
#pragma unroll
        for (int c = 0; c < 2; c++) {
            bf16x8 a = *(const bf16x8*)&Xs[arow * 72 + c * 32 + aoff];
            mfma_chunk(acc, a, Wb0 + c * 2048 + lane * 8);
        }
#pragma unroll
        for (int t = 0; t < 4; t++) {
            const int col = t * 16 + l15;
            const float b = ldf(b0, col, bf);
#pragma unroll
            for (int reg = 0; reg < 4; reg++)
                h1[(16 * w + q * 4 + reg) * 72 + col] = f2bf(gelu_f(acc[t][reg] + b));
        }
    }
    zero4(acc);
    {
#pragma unroll
        for (int c = 0; c < 2; c++) {
            bf16x8 a = *(const bf16x8*)&h1[arow * 72 + c * 32 + aoff];
            mfma_chunk(acc, a, Wb1 + c * 2048 + lane * 8);
        }
#pragma unroll
        for (int t = 0; t < 4; t++) {
            const int col = t * 16 + l15;
            const float b = ldf(b1, col, bf);
#pragma unroll
            for (int reg = 0; reg < 4; reg++)
                h2[(16 * w + q * 4 + reg) * 72 + col] = f2bf(gelu_f(acc[t][reg] + b));
        }
    }
    __syncthreads();
    const int col = tid & 63;
    const int r0 = (tid >> 6) * 16;
    if (col < 3) {
        float a[16];
        const float b = ldf(b2, col, bf);
#pragma unroll
        for (int i = 0; i < 16; i++) a[i] = b;
        for (int k = 0; k < 64; k++) {
            float wv = ldf(W2, (long)k * 3 + col, bf);
#pragma unroll
            for (int i = 0; i < 16; i++) a[i] = fmaf(bf2f(h2[(r0 + i) * 72 + k]), wv, a[i]);
        }
        for (int i = 0; i < 16; i++) {
            const long idx = rb + r0 + i;
            if (idx < N_NODES) {
                if (bf)
                    ((unsigned short*)outp)[idx * 3 + col] = f2bf(a[i]);
                else
                    ((float*)outp)[idx * 3 + col] = a[i];
            }
        }
    }
}

// ---------- launch ----------
extern "C" void kernel_launch(void* const* d_in, const int* in_sizes, int n_in, void* d_out,
                              int out_size, void* d_ws, size_t ws_size, hipStream_t stream) {
    const void* nodes = d_in[0];
    const void* edges = d_in[1];
    const void* glob = d_in[2];
    const void *enW0 = d_in[3], *enb0 = d_in[4], *enW1 = d_in[5], *enb1 = d_in[6],
               *enW2 = d_in[7], *enb2 = d_in[8];
    const void *eeW0 = d_in[9], *eeb0 = d_in[10], *eeW1 = d_in[11], *eeb1 = d_in[12],
               *eeW2 = d_in[13], *eeb2 = d_in[14];
    const void *eW0 = d_in[15], *eb0 = d_in[16], *eW1 = d_in[17], *eb1 = d_in[18],
               *eW2 = d_in[19], *eb2 = d_in[20];
    const void *nW0 = d_in[21], *nb0 = d_in[22], *nW1 = d_in[23], *nb1 = d_in[24],
               *nW2 = d_in[25], *nb2 = d_in[26];
    const void *lnns = d_in[27], *lnnb = d_in[28], *lnes = d_in[29], *lneb = d_in[30];
    const void *dW0 = d_in[31], *db0 = d_in[32], *dW1 = d_in[33], *db1 = d_in[34],
               *dW2 = d_in[35], *db2 = d_in[36];
    const int* senders = (const int*)d_in[37];
    const int* receivers = (const int*)d_in[38];

    // workspace layout
    float* n_lat = (float*)d_ws;                 // 3,200,000 f32
    float* recvb = n_lat + 3200000;              // 3,200,000 f32
    float* b0eff_e = recvb + 3200000;            // 192
    float* b0eff_n = b0eff_e + 192;              // 192
    int* flag = (int*)(b0eff_n + 192);           // pad to 64 f32
    unsigned short* e_lat = (unsigned short*)(b0eff_n + 256);  // 51,200,000 bf16
    unsigned short* WbBase = e_lat + 51200000;   // 139,264 bf16
    unsigned short* WbE0 = WbBase;               // offsets per prep_all table
    unsigned short* WbE1 = WbBase + 36864;
    unsigned short* WbE2 = WbBase + 49152;
    unsigned short* WbN0 = WbBase + 61440;
    unsigned short* WbN1 = WbBase + 86016;
    unsigned short* WbN2 = WbBase + 98304;
    unsigned short* WbNE0 = WbBase + 110592;
    unsigned short* WbNE1 = WbBase + 112640;
    unsigned short* WbNE2 = WbBase + 116736;
    unsigned short* WbEE0 = WbBase + 120832;
    unsigned short* WbEE1 = WbBase + 122880;
    unsigned short* WbEE2 = WbBase + 126976;
    unsigned short* WbD0 = WbBase + 131072;
    unsigned short* WbD1 = WbBase + 135168;

    detect_kernel<<<1, 64, 0, stream>>>(lnns, flag);

    PrepPtrs pp;
    pp.W[0] = eW0;  pp.W[1] = eW1;  pp.W[2] = eW2;
    pp.W[3] = nW0;  pp.W[4] = nW1;  pp.W[5] = nW2;
    pp.W[6] = enW0; pp.W[7] = enW1; pp.W[8] = enW2;
    pp.W[9] = eeW0; pp.W[10] = eeW1; pp.W[11] = eeW2;
    pp.W[12] = dW0; pp.W[13] = dW1;
    pp.eb0 = eb0; pp.nb0 = nb0; pp.glob = glob;
    prep_all<<<(PREP_WTOTAL + 384 + 255) / 256, 256, 0, stream>>>(pp, WbBase, b0eff_e, b0eff_n,
                                                                  flag);
    hipMemsetAsync(recvb, 0, (size_t)N_NODES * 64 * sizeof(float), stream);

    embed_mfma<7, 0><<<(N_NODES + 63) / 64, 256, 0, stream>>>(
        nodes, WbNE0, enb0, WbNE1, enb1, WbNE2, enb2, n_lat, N_NODES, flag);
    embed_mfma<4, 1><<<N_EDGES / 64, 256, 0, stream>>>(
        edges, WbEE0, eeb0, WbEE1, eeb1, WbEE2, eeb2, e_lat, N_EDGES, flag);
    for (int s = 0; s < NSTEPS; s++) {
        edge_update_mfma<<<N_EDGES / 64, 256, 0, stream>>>(
            e_lat, n_lat, senders, receivers, WbE0, WbE1, WbE2, b0eff_e, eb1, eb2, lnes, lneb,
            recvb, s, flag);
        node_update_mfma<<<(N_NODES + 63) / 64, 256, 0, stream>>>(
            n_lat, recvb, WbN0, b0eff_n, WbN1, nb1, WbN2, nb2, lnns, lnnb, s, flag);
    }
    decoder_mfma<<<(N_NODES + 63) / 64, 256, 0, stream>>>(n_lat, WbD0, db0, WbD1, db1, dW2,
                                                          db2, d_out, flag);
}